// Round 1
// baseline (34178.561 us; speedup 1.0000x reference)
//
#include <hip/hip_runtime.h>
#include <hip/hip_bf16.h>
#include <math.h>

constexpr int BB   = 32;
constexpr int DD   = 768;
constexpr int LL   = 197;
constexpr int HH   = 12;
constexpr int NTOK = 196;
constexpr int MROWS = BB * LL;   // 6304

// ---------------------------------------------------------------------------
// Patch embed: patchify + t = p @ W^T + b + LayerNorm, one block per token
// ---------------------------------------------------------------------------
__global__ __launch_bounds__(256) void patch_embed_kernel(
    const float* __restrict__ src, int C,
    const float* __restrict__ w, const float* __restrict__ pb,
    const float* __restrict__ g, const float* __restrict__ beta,
    float* __restrict__ out)
{
    int n = blockIdx.x;            // 0..195
    int b = blockIdx.y;
    int tid = threadIdx.x;
    int K = C * 256;
    __shared__ float p[768];
    __shared__ float red[256];
    int i14 = n / 14, j14 = n % 14;
    const float* sb = src + (size_t)b * C * 224 * 224;
    for (int k = tid; k < K; k += 256) {
        int c = k >> 8, rem = k & 255;
        int pi = rem >> 4, pj = rem & 15;
        p[k] = sb[(size_t)c * 224 * 224 + (i14 * 16 + pi) * 224 + (j14 * 16 + pj)];
    }
    __syncthreads();
    float t[3];
    #pragma unroll
    for (int r = 0; r < 3; ++r) {
        int d = tid + r * 256;
        const float* wr = w + (size_t)d * K;
        float acc = pb[d];
        for (int k = 0; k < K; k += 4) {
            float4 wv = *reinterpret_cast<const float4*>(wr + k);
            acc += p[k] * wv.x + p[k+1] * wv.y + p[k+2] * wv.z + p[k+3] * wv.w;
        }
        t[r] = acc;
    }
    // LayerNorm over 768 (two-pass)
    red[tid] = t[0] + t[1] + t[2];
    __syncthreads();
    for (int off = 128; off; off >>= 1) {
        if (tid < off) red[tid] += red[tid + off];
        __syncthreads();
    }
    float mean = red[0] * (1.f / 768.f);
    __syncthreads();
    float q = 0.f;
    #pragma unroll
    for (int r = 0; r < 3; ++r) { float dv = t[r] - mean; q += dv * dv; }
    red[tid] = q;
    __syncthreads();
    for (int off = 128; off; off >>= 1) {
        if (tid < off) red[tid] += red[tid + off];
        __syncthreads();
    }
    float rstd = rsqrtf(red[0] * (1.f / 768.f) + 1e-5f);
    float* orow = out + ((size_t)(b * NTOK + n)) * DD;
    #pragma unroll
    for (int r = 0; r < 3; ++r) {
        int d = tid + r * 256;
        orow[d] = g[d] * (t[r] - mean) * rstd + beta[d];
    }
}

// ---------------------------------------------------------------------------
// Attention bias: bias[b,1+i,1+j] = dot(tok_m[b,i], tok_m[b,j]) / sqrt(768)
// ---------------------------------------------------------------------------
__global__ __launch_bounds__(256) void bias_kernel(
    const float* __restrict__ tokm, float* __restrict__ bias)
{
    int b = blockIdx.z;
    int i0 = blockIdx.y * 16, j0 = blockIdx.x * 16;
    int tx = threadIdx.x & 15, ty = threadIdx.x >> 4;
    __shared__ float Ai[16][17];
    __shared__ float Aj[16][17];
    const float* tb = tokm + (size_t)b * NTOK * DD;
    float acc = 0.f;
    for (int k0 = 0; k0 < DD; k0 += 16) {
        int ri = i0 + ty;
        Ai[ty][tx] = (ri < NTOK) ? tb[(size_t)ri * DD + k0 + tx] : 0.f;
        int rj = j0 + ty;
        Aj[ty][tx] = (rj < NTOK) ? tb[(size_t)rj * DD + k0 + tx] : 0.f;
        __syncthreads();
        #pragma unroll
        for (int k = 0; k < 16; ++k) acc += Ai[ty][k] * Aj[tx][k];
        __syncthreads();
    }
    int i = i0 + ty, j = j0 + tx;
    if (i < NTOK && j < NTOK)
        bias[((size_t)b * LL + (i + 1)) * LL + (j + 1)] = acc * 0.03608439182435161f;
}

__global__ void bias_edge_kernel(float* __restrict__ bias)
{
    int b = blockIdx.x, t = threadIdx.x;
    if (t < LL) {
        bias[((size_t)b * LL + 0) * LL + t] = 0.f;
        bias[((size_t)b * LL + t) * LL + 0] = 0.f;
    }
}

// ---------------------------------------------------------------------------
// x = [cls ; tok_i + 0.5 tok_m] + pos
// ---------------------------------------------------------------------------
__global__ void combine_kernel(
    const float* __restrict__ toki, const float* __restrict__ tokm,
    const float* __restrict__ cls, const float* __restrict__ pos,
    float* __restrict__ x)
{
    size_t idx = (size_t)blockIdx.x * 256 + threadIdx.x;
    if (idx >= (size_t)MROWS * DD) return;
    int d = (int)(idx % DD);
    size_t bl = idx / DD;
    int l = (int)(bl % LL);
    int b = (int)(bl / LL);
    float v;
    if (l == 0) v = cls[d];
    else {
        size_t tix = ((size_t)b * NTOK + (l - 1)) * DD + d;
        v = toki[tix] + 0.5f * tokm[tix];
    }
    x[idx] = v + pos[(size_t)l * DD + d];
}

// ---------------------------------------------------------------------------
// Row LayerNorm (two-pass), one block per row
// ---------------------------------------------------------------------------
__global__ __launch_bounds__(256) void ln_kernel(
    const float* __restrict__ in, const float* __restrict__ g,
    const float* __restrict__ beta, float* __restrict__ out)
{
    int row = blockIdx.x;
    int tid = threadIdx.x;
    const float* xr = in + (size_t)row * DD;
    float v[3];
    #pragma unroll
    for (int r = 0; r < 3; ++r) v[r] = xr[tid + r * 256];
    __shared__ float red[256];
    red[tid] = v[0] + v[1] + v[2];
    __syncthreads();
    for (int off = 128; off; off >>= 1) {
        if (tid < off) red[tid] += red[tid + off];
        __syncthreads();
    }
    float mean = red[0] * (1.f / 768.f);
    __syncthreads();
    float q = 0.f;
    #pragma unroll
    for (int r = 0; r < 3; ++r) { float dv = v[r] - mean; q += dv * dv; }
    red[tid] = q;
    __syncthreads();
    for (int off = 128; off; off >>= 1) {
        if (tid < off) red[tid] += red[tid + off];
        __syncthreads();
    }
    float rstd = rsqrtf(red[0] * (1.f / 768.f) + 1e-5f);
    float* orow = out + (size_t)row * DD;
    #pragma unroll
    for (int r = 0; r < 3; ++r) {
        int d = tid + r * 256;
        orow[d] = g[d] * (v[r] - mean) * rstd + beta[d];
    }
}

// ---------------------------------------------------------------------------
// Generic f32 GEMM: C[m,n] = A[m,:] . W[n,:] + bias[n]  (64x64 tile, 4x4/thr)
// MODE 0 = plain, 1 = exact GELU, 2 = + res[m,n]
// ---------------------------------------------------------------------------
template<int MODE>
__global__ __launch_bounds__(256) void gemm_kernel(
    const float* __restrict__ A, const float* __restrict__ W,
    const float* __restrict__ bias, const float* __restrict__ res,
    float* __restrict__ C, int M, int N, int K)
{
    __shared__ float As[64][17];
    __shared__ float Ws[64][17];
    int tid = threadIdx.x;
    int m0 = blockIdx.y * 64, n0 = blockIdx.x * 64;
    int tx = tid & 15, ty = tid >> 4;
    int lrow = tid >> 2, lcol = (tid & 3) * 4;
    float acc[4][4] = {};
    for (int k0 = 0; k0 < K; k0 += 16) {
        int am = m0 + lrow;
        float4 av = make_float4(0.f, 0.f, 0.f, 0.f);
        if (am < M) av = *reinterpret_cast<const float4*>(A + (size_t)am * K + k0 + lcol);
        As[lrow][lcol]   = av.x; As[lrow][lcol+1] = av.y;
        As[lrow][lcol+2] = av.z; As[lrow][lcol+3] = av.w;
        float4 wv = *reinterpret_cast<const float4*>(W + (size_t)(n0 + lrow) * K + k0 + lcol);
        Ws[lrow][lcol]   = wv.x; Ws[lrow][lcol+1] = wv.y;
        Ws[lrow][lcol+2] = wv.z; Ws[lrow][lcol+3] = wv.w;
        __syncthreads();
        #pragma unroll
        for (int k = 0; k < 16; ++k) {
            float a[4], w4[4];
            #pragma unroll
            for (int i = 0; i < 4; ++i) a[i] = As[ty + 16 * i][k];
            #pragma unroll
            for (int j = 0; j < 4; ++j) w4[j] = Ws[tx + 16 * j][k];
            #pragma unroll
            for (int i = 0; i < 4; ++i)
                #pragma unroll
                for (int j = 0; j < 4; ++j)
                    acc[i][j] += a[i] * w4[j];
        }
        __syncthreads();
    }
    #pragma unroll
    for (int i = 0; i < 4; ++i) {
        int m = m0 + ty + 16 * i;
        if (m >= M) continue;
        #pragma unroll
        for (int j = 0; j < 4; ++j) {
            int n = n0 + tx + 16 * j;
            float v = acc[i][j] + bias[n];
            if (MODE == 1) v = 0.5f * v * (1.f + erff(v * 0.70710678118654752f));
            if (MODE == 2) v += res[(size_t)m * N + n];
            C[(size_t)m * N + n] = v;
        }
    }
}

// ---------------------------------------------------------------------------
// Fused attention: one block per (b, h, query row). Row softmax with bias.
// ---------------------------------------------------------------------------
__global__ __launch_bounds__(256) void attn_kernel(
    const float* __restrict__ qkv, const float* __restrict__ bias,
    float* __restrict__ o)
{
    int qi = blockIdx.x, hh = blockIdx.y, b = blockIdx.z;
    int tid = threadIdx.x;
    __shared__ float qs[64];
    __shared__ float sc[256];
    __shared__ float red[256];
    if (tid < 64) qs[tid] = qkv[((size_t)(b * LL + qi)) * 2304 + hh * 64 + tid];
    __syncthreads();
    float s = -1e30f;
    if (tid < LL) {
        const float* krow = qkv + ((size_t)(b * LL + tid)) * 2304 + 768 + hh * 64;
        float acc = 0.f;
        #pragma unroll
        for (int d = 0; d < 64; d += 4) {
            float4 kv = *reinterpret_cast<const float4*>(krow + d);
            acc += qs[d] * kv.x + qs[d+1] * kv.y + qs[d+2] * kv.z + qs[d+3] * kv.w;
        }
        s = acc * 0.125f + bias[((size_t)b * LL + qi) * LL + tid];
    }
    red[tid] = s;
    __syncthreads();
    for (int off = 128; off; off >>= 1) {
        if (tid < off) red[tid] = fmaxf(red[tid], red[tid + off]);
        __syncthreads();
    }
    float mx = red[0];
    __syncthreads();
    float e = (tid < LL) ? __expf(s - mx) : 0.f;
    sc[tid] = e;
    red[tid] = e;
    __syncthreads();
    for (int off = 128; off; off >>= 1) {
        if (tid < off) red[tid] += red[tid + off];
        __syncthreads();
    }
    float inv = 1.f / red[0];
    if (tid < 64) {
        float acc = 0.f;
        for (int j = 0; j < LL; ++j)
            acc += sc[j] * qkv[((size_t)(b * LL + j)) * 2304 + 1536 + hh * 64 + tid];
        o[((size_t)(b * LL + qi)) * DD + hh * 64 + tid] = acc * inv;
    }
}

// ---------------------------------------------------------------------------
// Final: LN(enc) -> LN(fin) on the CLS row only, then 4-class head
// ---------------------------------------------------------------------------
__global__ __launch_bounds__(256) void final_kernel(
    const float* __restrict__ x,
    const float* __restrict__ eg, const float* __restrict__ eb,
    const float* __restrict__ fg, const float* __restrict__ fb,
    const float* __restrict__ hw, const float* __restrict__ hb,
    float* __restrict__ out)
{
    int b = blockIdx.x;
    int tid = threadIdx.x;
    __shared__ float xs[768];
    __shared__ float red[256];
    const float* xr = x + (size_t)b * LL * DD;   // CLS row
    #pragma unroll
    for (int r = 0; r < 3; ++r) xs[tid + r * 256] = xr[tid + r * 256];
    __syncthreads();
    for (int pass = 0; pass < 2; ++pass) {
        const float* g  = pass ? fg : eg;
        const float* bb = pass ? fb : eb;
        red[tid] = xs[tid] + xs[tid + 256] + xs[tid + 512];
        __syncthreads();
        for (int off = 128; off; off >>= 1) {
            if (tid < off) red[tid] += red[tid + off];
            __syncthreads();
        }
        float mean = red[0] * (1.f / 768.f);
        __syncthreads();
        float q = 0.f;
        #pragma unroll
        for (int r = 0; r < 3; ++r) { float dv = xs[tid + r * 256] - mean; q += dv * dv; }
        red[tid] = q;
        __syncthreads();
        for (int off = 128; off; off >>= 1) {
            if (tid < off) red[tid] += red[tid + off];
            __syncthreads();
        }
        float rstd = rsqrtf(red[0] * (1.f / 768.f) + 1e-5f);
        __syncthreads();
        #pragma unroll
        for (int r = 0; r < 3; ++r) {
            int d = tid + r * 256;
            xs[d] = g[d] * (xs[d] - mean) * rstd + bb[d];
        }
        __syncthreads();
    }
    int c = tid >> 6, lane = tid & 63;
    float part = 0.f;
    for (int d = lane; d < 768; d += 64) part += xs[d] * hw[c * 768 + d];
    #pragma unroll
    for (int off = 32; off; off >>= 1) part += __shfl_down(part, off);
    if (lane == 0) out[b * 4 + c] = part + hb[c];
}

// ---------------------------------------------------------------------------
extern "C" void kernel_launch(void* const* d_in, const int* in_sizes, int n_in,
                              void* d_out, int out_size, void* d_ws, size_t ws_size,
                              hipStream_t stream)
{
    const float* img    = (const float*)d_in[0];
    const float* mask   = (const float*)d_in[1];
    const float* pe_iw  = (const float*)d_in[2];
    const float* pe_ib  = (const float*)d_in[3];
    const float* pe_ig  = (const float*)d_in[4];
    const float* pe_ibb = (const float*)d_in[5];
    const float* pe_mw  = (const float*)d_in[6];
    const float* pe_mb  = (const float*)d_in[7];
    const float* pe_mg  = (const float*)d_in[8];
    const float* pe_mbb = (const float*)d_in[9];
    const float* cls    = (const float*)d_in[10];
    const float* pos    = (const float*)d_in[11];
    const float* ln1_g  = (const float*)d_in[12];
    const float* ln1_b  = (const float*)d_in[13];
    const float* w_qkv  = (const float*)d_in[14];
    const float* b_qkv  = (const float*)d_in[15];
    const float* w_out  = (const float*)d_in[16];
    const float* b_out  = (const float*)d_in[17];
    const float* ln2_g  = (const float*)d_in[18];
    const float* ln2_b  = (const float*)d_in[19];
    const float* w_fc1  = (const float*)d_in[20];
    const float* b_fc1  = (const float*)d_in[21];
    const float* w_fc2  = (const float*)d_in[22];
    const float* b_fc2  = (const float*)d_in[23];
    const float* enc_g  = (const float*)d_in[24];
    const float* enc_b  = (const float*)d_in[25];
    const float* fin_g  = (const float*)d_in[26];
    const float* fin_b  = (const float*)d_in[27];
    const float* head_w = (const float*)d_in[28];
    const float* head_b = (const float*)d_in[29];

    float* ws   = (float*)d_ws;
    float* x    = ws;                               // 6304*768
    float* h    = x   + (size_t)MROWS * DD;         // 6304*768
    float* qkv  = h   + (size_t)MROWS * DD;         // 6304*2304
    float* fc1  = qkv + (size_t)MROWS * 3 * DD;     // 6304*3072
    float* biasb= fc1 + (size_t)MROWS * 4 * DD;     // 32*197*197
    float* toki = qkv;   // alias: dead before qkv first written
    float* tokm = fc1;   // alias: dead before fc1 first written

    patch_embed_kernel<<<dim3(NTOK, BB), 256, 0, stream>>>(img, 3, pe_iw, pe_ib, pe_ig, pe_ibb, toki);
    patch_embed_kernel<<<dim3(NTOK, BB), 256, 0, stream>>>(mask, 1, pe_mw, pe_mb, pe_mg, pe_mbb, tokm);
    bias_kernel<<<dim3(13, 13, BB), 256, 0, stream>>>(tokm, biasb);
    bias_edge_kernel<<<BB, 256, 0, stream>>>(biasb);
    combine_kernel<<<(MROWS * DD + 255) / 256, 256, 0, stream>>>(toki, tokm, cls, pos, x);

    int mblk = (MROWS + 63) / 64;
    for (int l = 0; l < 12; ++l) {
        ln_kernel<<<MROWS, 256, 0, stream>>>(x, ln1_g + l * DD, ln1_b + l * DD, h);
        gemm_kernel<0><<<dim3(2304 / 64, mblk), 256, 0, stream>>>(
            h, w_qkv + (size_t)l * 2304 * DD, b_qkv + l * 2304, nullptr, qkv, MROWS, 2304, DD);
        attn_kernel<<<dim3(LL, HH, BB), 256, 0, stream>>>(qkv, biasb, h);
        gemm_kernel<2><<<dim3(DD / 64, mblk), 256, 0, stream>>>(
            h, w_out + (size_t)l * DD * DD, b_out + l * DD, x, x, MROWS, DD, DD);
        ln_kernel<<<MROWS, 256, 0, stream>>>(x, ln2_g + l * DD, ln2_b + l * DD, h);
        gemm_kernel<1><<<dim3(3072 / 64, mblk), 256, 0, stream>>>(
            h, w_fc1 + (size_t)l * 3072 * DD, b_fc1 + l * 3072, nullptr, fc1, MROWS, 3072, DD);
        gemm_kernel<2><<<dim3(DD / 64, mblk), 256, 0, stream>>>(
            fc1, w_fc2 + (size_t)l * DD * 3072, b_fc2 + l * DD, x, x, MROWS, DD, 3072);
    }
    final_kernel<<<BB, 256, 0, stream>>>(x, enc_g, enc_b, fin_g, fin_b, head_w, head_b, (float*)d_out);
}

// Round 2
// 10807.608 us; speedup vs baseline: 3.1625x; 3.1625x over previous
//
#include <hip/hip_runtime.h>
#include <hip/hip_bf16.h>
#include <math.h>

typedef unsigned int   u32;
typedef unsigned short u16;
typedef __bf16 bf16x8 __attribute__((ext_vector_type(8)));
typedef float  f32x4  __attribute__((ext_vector_type(4)));
typedef u16    u16x8  __attribute__((ext_vector_type(8)));
typedef float  f32x4v __attribute__((ext_vector_type(4)));

constexpr int BB = 32, DD = 768, LL = 197, HH = 12, NTOK = 196;
constexpr int MROWS = BB * LL;        // 6304
constexpr int MTOK  = BB * NTOK;      // 6272

__device__ __forceinline__ u16 f2bf(float f) {
    union { float f; u32 u; } v; v.f = f;
    u32 r = v.u + 0x7fff + ((v.u >> 16) & 1);
    return (u16)(r >> 16);
}
__device__ __forceinline__ float bf2f(u16 u) {
    union { u32 u; float f; } v; v.u = ((u32)u) << 16;
    return v.f;
}

#define AS1 __attribute__((address_space(1)))
#define AS3 __attribute__((address_space(3)))
__device__ __forceinline__ void gload_lds16(const void* g, void* l) {
    __builtin_amdgcn_global_load_lds((const AS1 u32*)g, (AS3 u32*)l, 16, 0, 0);
}

// ---------------------------------------------------------------------------
// f32 -> bf16 cast (float4 / 4 elems per thread, n % 4 == 0)
// ---------------------------------------------------------------------------
__global__ void cast_kernel(const float* __restrict__ in, u16* __restrict__ out, int n)
{
    int i4 = (blockIdx.x * 256 + threadIdx.x) * 4;
    if (i4 >= n) return;
    float4 v = *reinterpret_cast<const float4*>(in + i4);
    out[i4]   = f2bf(v.x); out[i4+1] = f2bf(v.y);
    out[i4+2] = f2bf(v.z); out[i4+3] = f2bf(v.w);
}

// cast 4 weight tensors in one launch (all sizes % 4 == 0)
__global__ void cast4_kernel(const float* s0, int n0, const float* s1, int n1,
                             const float* s2, int n2, const float* s3, int n3,
                             u16* d0, u16* d1, u16* d2, u16* d3)
{
    int i4 = (blockIdx.x * 256 + threadIdx.x) * 4;
    const float* s; u16* d; int off;
    if      (i4 < n0)            { s = s0; d = d0; off = i4; }
    else if (i4 < n0+n1)         { s = s1; d = d1; off = i4 - n0; }
    else if (i4 < n0+n1+n2)      { s = s2; d = d2; off = i4 - n0 - n1; }
    else if (i4 < n0+n1+n2+n3)   { s = s3; d = d3; off = i4 - n0 - n1 - n2; }
    else return;
    float4 v = *reinterpret_cast<const float4*>(s + off);
    d[off]   = f2bf(v.x); d[off+1] = f2bf(v.y);
    d[off+2] = f2bf(v.z); d[off+3] = f2bf(v.w);
}

// ---------------------------------------------------------------------------
// Patchify: img [B,C,224,224] f32 -> patches [B*196, C*256] bf16
// ---------------------------------------------------------------------------
__global__ void patchify_kernel(const float* __restrict__ src, int C,
                                u16* __restrict__ out, int total)
{
    int idx = blockIdx.x * 256 + threadIdx.x;
    if (idx >= total) return;
    int K = C * 256;
    int row = idx / K, k = idx % K;
    int b = row / NTOK, n = row % NTOK;
    int c = k >> 8, rem = k & 255, pi = rem >> 4, pj = rem & 15;
    int i14 = n / 14, j14 = n % 14;
    float v = src[(((size_t)b * C + c) * 224 + i14 * 16 + pi) * 224 + j14 * 16 + pj];
    out[idx] = f2bf(v);
}

// ---------------------------------------------------------------------------
// bf16 MFMA GEMM: C[m,n] = A[m,:] . W[n,:] (+bias) — 128x128 tile, 4 waves,
// 16x16x32 MFMA, global_load_lds staging (m97 structure).
// MODE 0: f32 out +bias          MODE 1: GELU -> bf16 out, +bias
// MODE 2: f32 out +bias+res      MODE 3: batched bias-GEMM (special epilogue)
// MODE 4: bf16 out +bias
// ---------------------------------------------------------------------------
template<int MODE>
__global__ __launch_bounds__(256) void gemm_bf16(
    const u16* __restrict__ A, const u16* __restrict__ W,
    const float* __restrict__ bias, const float* __restrict__ res,
    void* __restrict__ Cout, int M, int N, int K, long long strideA)
{
    __shared__ u16 As[128 * 32];
    __shared__ u16 Bs[128 * 32];
    const int tid  = threadIdx.x;
    const int wave = tid >> 6, lane = tid & 63;
    const int wr = wave >> 1, wc = wave & 1;
    const int m0 = blockIdx.y * 128, n0 = blockIdx.x * 128;
    if (MODE == 3) { A += blockIdx.z * strideA; W += blockIdx.z * strideA; }

    const int srow = (wave << 4) + (lane >> 2);   // 0..63
    const int scol = (lane & 3) << 3;             // 0,8,16,24
    const int limA = M - 1;
    const int limB = (MODE == 3 ? M : N) - 1;
    int ra0 = m0 + srow;      if (ra0 > limA) ra0 = limA;
    int ra1 = m0 + srow + 64; if (ra1 > limA) ra1 = limA;
    int rb0 = n0 + srow;      if (rb0 > limB) rb0 = limB;
    int rb1 = n0 + srow + 64; if (rb1 > limB) rb1 = limB;

    u16* ldsA0 = &As[wave * 512];
    u16* ldsA1 = &As[2048 + wave * 512];
    u16* ldsB0 = &Bs[wave * 512];
    u16* ldsB1 = &Bs[2048 + wave * 512];

    f32x4 acc[4][4] = {};
    const int rfA = wr * 64 + (lane & 15);
    const int rfB = wc * 64 + (lane & 15);
    const int kc  = (lane >> 4) * 8;

    for (int k0 = 0; k0 < K; k0 += 32) {
        gload_lds16(A + (size_t)ra0 * K + k0 + scol, ldsA0);
        gload_lds16(A + (size_t)ra1 * K + k0 + scol, ldsA1);
        gload_lds16(W + (size_t)rb0 * K + k0 + scol, ldsB0);
        gload_lds16(W + (size_t)rb1 * K + k0 + scol, ldsB1);
        __syncthreads();
        bf16x8 af[4], bf[4];
        #pragma unroll
        for (int i = 0; i < 4; ++i)
            af[i] = *reinterpret_cast<const bf16x8*>(&As[(rfA + i * 16) * 32 + kc]);
        #pragma unroll
        for (int j = 0; j < 4; ++j)
            bf[j] = *reinterpret_cast<const bf16x8*>(&Bs[(rfB + j * 16) * 32 + kc]);
        #pragma unroll
        for (int i = 0; i < 4; ++i)
            #pragma unroll
            for (int j = 0; j < 4; ++j)
                acc[i][j] = __builtin_amdgcn_mfma_f32_16x16x32_bf16(af[i], bf[j], acc[i][j], 0, 0, 0);
        __syncthreads();
    }

    const int cr = (lane >> 4) * 4;
    const int cc = lane & 15;
    #pragma unroll
    for (int i = 0; i < 4; ++i) {
        #pragma unroll
        for (int r = 0; r < 4; ++r) {
            int m = m0 + wr * 64 + i * 16 + cr + r;
            if (MODE != 3 && m >= M) continue;
            #pragma unroll
            for (int j = 0; j < 4; ++j) {
                int n = n0 + wc * 64 + j * 16 + cc;
                float v = acc[i][j][r];
                if (MODE == 0) {
                    ((float*)Cout)[(size_t)m * N + n] = v + bias[n];
                } else if (MODE == 1) {
                    float t = v + bias[n];
                    t = 0.5f * t * (1.f + erff(t * 0.70710678118654752f));
                    ((u16*)Cout)[(size_t)m * N + n] = f2bf(t);
                } else if (MODE == 2) {
                    ((float*)Cout)[(size_t)m * N + n] = v + bias[n] + res[(size_t)m * N + n];
                } else if (MODE == 4) {
                    ((u16*)Cout)[(size_t)m * N + n] = f2bf(v + bias[n]);
                } else { // MODE 3
                    if (m < M && n < M) {
                        float* C3 = (float*)Cout + (size_t)blockIdx.z * LL * LL;
                        C3[(size_t)(m + 1) * LL + (n + 1)] = v * 0.03608439182435161f;
                    }
                }
            }
        }
    }
}

__global__ void bias_edge_kernel(float* __restrict__ bias)
{
    int b = blockIdx.x, t = threadIdx.x;
    if (t < LL) {
        bias[((size_t)b * LL + 0) * LL + t] = 0.f;
        bias[((size_t)b * LL + t) * LL + 0] = 0.f;
    }
}

// ---------------------------------------------------------------------------
// x = [cls ; tok_i + 0.5 tok_m] + pos  (f32)
// ---------------------------------------------------------------------------
__global__ void combine_kernel(
    const float* __restrict__ toki, const float* __restrict__ tokm,
    const float* __restrict__ cls, const float* __restrict__ pos,
    float* __restrict__ x)
{
    size_t idx = (size_t)blockIdx.x * 256 + threadIdx.x;
    if (idx >= (size_t)MROWS * DD) return;
    int d = (int)(idx % DD);
    size_t bl = idx / DD;
    int l = (int)(bl % LL);
    int b = (int)(bl / LL);
    float v;
    if (l == 0) v = cls[d];
    else {
        size_t tix = ((size_t)b * NTOK + (l - 1)) * DD + d;
        v = toki[tix] + 0.5f * tokm[tix];
    }
    x[idx] = v + pos[(size_t)l * DD + d];
}

// ---------------------------------------------------------------------------
// Row LayerNorm. OUT: 0 = f32 only, 1 = bf16 only, 2 = both
// ---------------------------------------------------------------------------
template<int OUT>
__global__ __launch_bounds__(256) void ln_kernel(
    const float* __restrict__ in, const float* __restrict__ g,
    const float* __restrict__ beta, float* __restrict__ outf,
    u16* __restrict__ outb)
{
    int row = blockIdx.x;
    int tid = threadIdx.x;
    const float* xr = in + (size_t)row * DD;
    float v[3];
    #pragma unroll
    for (int r = 0; r < 3; ++r) v[r] = xr[tid + r * 256];
    __shared__ float red[256];
    red[tid] = v[0] + v[1] + v[2];
    __syncthreads();
    for (int off = 128; off; off >>= 1) {
        if (tid < off) red[tid] += red[tid + off];
        __syncthreads();
    }
    float mean = red[0] * (1.f / 768.f);
    __syncthreads();
    float q = 0.f;
    #pragma unroll
    for (int r = 0; r < 3; ++r) { float dv = v[r] - mean; q += dv * dv; }
    red[tid] = q;
    __syncthreads();
    for (int off = 128; off; off >>= 1) {
        if (tid < off) red[tid] += red[tid + off];
        __syncthreads();
    }
    float rstd = rsqrtf(red[0] * (1.f / 768.f) + 1e-5f);
    #pragma unroll
    for (int r = 0; r < 3; ++r) {
        int d = tid + r * 256;
        float o = g[d] * (v[r] - mean) * rstd + beta[d];
        if (OUT == 0 || OUT == 2) outf[(size_t)row * DD + d] = o;
        if (OUT == 1 || OUT == 2) outb[(size_t)row * DD + d] = f2bf(o);
    }
}

// ---------------------------------------------------------------------------
// Fused attention: one block per (b, h, query row). bf16 qkv in, bf16 o out.
// ---------------------------------------------------------------------------
__global__ __launch_bounds__(256) void attn_kernel(
    const u16* __restrict__ qkv, const float* __restrict__ bias,
    u16* __restrict__ o)
{
    int qi = blockIdx.x, hh = blockIdx.y, b = blockIdx.z;
    int tid = threadIdx.x;
    __shared__ float qs[64];
    __shared__ float sc[256];
    __shared__ float red[256];
    if (tid < 64) qs[tid] = bf2f(qkv[((size_t)(b * LL + qi)) * 2304 + hh * 64 + tid]);
    __syncthreads();
    float s = -1e30f;
    if (tid < LL) {
        const u16* krow = qkv + ((size_t)(b * LL + tid)) * 2304 + 768 + hh * 64;
        float acc = 0.f;
        #pragma unroll
        for (int d0 = 0; d0 < 64; d0 += 8) {
            u16x8 kv = *reinterpret_cast<const u16x8*>(krow + d0);
            #pragma unroll
            for (int e = 0; e < 8; ++e) acc += qs[d0 + e] * bf2f(kv[e]);
        }
        s = acc * 0.125f + bias[((size_t)b * LL + qi) * LL + tid];
    }
    red[tid] = s;
    __syncthreads();
    for (int off = 128; off; off >>= 1) {
        if (tid < off) red[tid] = fmaxf(red[tid], red[tid + off]);
        __syncthreads();
    }
    float mx = red[0];
    __syncthreads();
    float e = (tid < LL) ? __expf(s - mx) : 0.f;
    sc[tid] = e;
    red[tid] = e;
    __syncthreads();
    for (int off = 128; off; off >>= 1) {
        if (tid < off) red[tid] += red[tid + off];
        __syncthreads();
    }
    float inv = 1.f / red[0];
    if (tid < 64) {
        float acc = 0.f;
        for (int j = 0; j < LL; ++j)
            acc += sc[j] * bf2f(qkv[((size_t)(b * LL + j)) * 2304 + 1536 + hh * 64 + tid]);
        o[((size_t)(b * LL + qi)) * DD + hh * 64 + tid] = f2bf(acc * inv);
    }
}

// ---------------------------------------------------------------------------
// Final: LN(enc) -> LN(fin) on CLS row only, then 4-class head
// ---------------------------------------------------------------------------
__global__ __launch_bounds__(256) void final_kernel(
    const float* __restrict__ x,
    const float* __restrict__ eg, const float* __restrict__ eb,
    const float* __restrict__ fg, const float* __restrict__ fb,
    const float* __restrict__ hw, const float* __restrict__ hb,
    float* __restrict__ out)
{
    int b = blockIdx.x;
    int tid = threadIdx.x;
    __shared__ float xs[768];
    __shared__ float red[256];
    const float* xr = x + (size_t)b * LL * DD;
    #pragma unroll
    for (int r = 0; r < 3; ++r) xs[tid + r * 256] = xr[tid + r * 256];
    __syncthreads();
    for (int pass = 0; pass < 2; ++pass) {
        const float* g  = pass ? fg : eg;
        const float* bb = pass ? fb : eb;
        red[tid] = xs[tid] + xs[tid + 256] + xs[tid + 512];
        __syncthreads();
        for (int off = 128; off; off >>= 1) {
            if (tid < off) red[tid] += red[tid + off];
            __syncthreads();
        }
        float mean = red[0] * (1.f / 768.f);
        __syncthreads();
        float q = 0.f;
        #pragma unroll
        for (int r = 0; r < 3; ++r) { float dv = xs[tid + r * 256] - mean; q += dv * dv; }
        red[tid] = q;
        __syncthreads();
        for (int off = 128; off; off >>= 1) {
            if (tid < off) red[tid] += red[tid + off];
            __syncthreads();
        }
        float rstd = rsqrtf(red[0] * (1.f / 768.f) + 1e-5f);
        __syncthreads();
        #pragma unroll
        for (int r = 0; r < 3; ++r) {
            int d = tid + r * 256;
            xs[d] = g[d] * (xs[d] - mean) * rstd + bb[d];
        }
        __syncthreads();
    }
    int c = tid >> 6, lane = tid & 63;
    float part = 0.f;
    for (int d = lane; d < 768; d += 64) part += xs[d] * hw[c * 768 + d];
    #pragma unroll
    for (int off = 32; off; off >>= 1) part += __shfl_down(part, off);
    if (lane == 0) out[b * 4 + c] = part + hb[c];
}

// ---------------------------------------------------------------------------
extern "C" void kernel_launch(void* const* d_in, const int* in_sizes, int n_in,
                              void* d_out, int out_size, void* d_ws, size_t ws_size,
                              hipStream_t stream)
{
    const float* img    = (const float*)d_in[0];
    const float* mask   = (const float*)d_in[1];
    const float* pe_iw  = (const float*)d_in[2];
    const float* pe_ib  = (const float*)d_in[3];
    const float* pe_ig  = (const float*)d_in[4];
    const float* pe_ibb = (const float*)d_in[5];
    const float* pe_mw  = (const float*)d_in[6];
    const float* pe_mb  = (const float*)d_in[7];
    const float* pe_mg  = (const float*)d_in[8];
    const float* pe_mbb = (const float*)d_in[9];
    const float* cls    = (const float*)d_in[10];
    const float* pos    = (const float*)d_in[11];
    const float* ln1_g  = (const float*)d_in[12];
    const float* ln1_b  = (const float*)d_in[13];
    const float* w_qkv  = (const float*)d_in[14];
    const float* b_qkv  = (const float*)d_in[15];
    const float* w_out  = (const float*)d_in[16];
    const float* b_out  = (const float*)d_in[17];
    const float* ln2_g  = (const float*)d_in[18];
    const float* ln2_b  = (const float*)d_in[19];
    const float* w_fc1  = (const float*)d_in[20];
    const float* b_fc1  = (const float*)d_in[21];
    const float* w_fc2  = (const float*)d_in[22];
    const float* b_fc2  = (const float*)d_in[23];
    const float* enc_g  = (const float*)d_in[24];
    const float* enc_b  = (const float*)d_in[25];
    const float* fin_g  = (const float*)d_in[26];
    const float* fin_b  = (const float*)d_in[27];
    const float* head_w = (const float*)d_in[28];
    const float* head_b = (const float*)d_in[29];

    char* wsb = (char*)d_ws;
    size_t off = 0;
    auto alloc = [&](size_t bytes) { void* p = wsb + off; off += (bytes + 255) & ~(size_t)255; return p; };

    float* x     = (float*)alloc((size_t)MROWS * DD * 4);
    u16*   qkvb  = (u16*)  alloc((size_t)MROWS * 3 * DD * 2);
    u16*   hbuf  = (u16*)  alloc((size_t)MROWS * DD * 2);
    u16*   fc1b  = (u16*)  alloc((size_t)MROWS * 4 * DD * 2);
    float* biasb = (float*)alloc((size_t)BB * LL * LL * 4);
    u16*   wqb   = (u16*)  alloc((size_t)3 * DD * DD * 2);
    u16*   wob   = (u16*)  alloc((size_t)DD * DD * 2);
    u16*   w1b   = (u16*)  alloc((size_t)4 * DD * DD * 2);
    u16*   w2b   = (u16*)  alloc((size_t)4 * DD * DD * 2);
    float* toki  = (float*)alloc((size_t)MTOK * DD * 4);
    float* tokm  = (float*)alloc((size_t)MTOK * DD * 4);
    // aliases (lifetimes disjoint):
    u16*   pa    = fc1b;           // patches, <= fc1b size
    float* ttmp  = (float*)qkvb;   // pe-GEMM f32 out, <= qkvb size
    u16*   tokmb = hbuf;           // bf16 tok_m for bias GEMM

    // ---- patch embed (img) ----
    cast_kernel<<<(DD * DD / 4 + 255) / 256, 256, 0, stream>>>(pe_iw, wob, DD * DD);
    patchify_kernel<<<(MTOK * DD + 255) / 256, 256, 0, stream>>>(img, 3, pa, MTOK * DD);
    gemm_bf16<0><<<dim3(DD / 128, MTOK / 128), 256, 0, stream>>>(
        pa, wob, pe_ib, nullptr, ttmp, MTOK, DD, DD, 0);
    ln_kernel<0><<<MTOK, 256, 0, stream>>>(ttmp, pe_ig, pe_ibb, toki, nullptr);

    // ---- patch embed (mask) ----
    cast_kernel<<<(DD * 256 / 4 + 255) / 256, 256, 0, stream>>>(pe_mw, wob, DD * 256);
    patchify_kernel<<<(MTOK * 256 + 255) / 256, 256, 0, stream>>>(mask, 1, pa, MTOK * 256);
    gemm_bf16<0><<<dim3(DD / 128, MTOK / 128), 256, 0, stream>>>(
        pa, wob, pe_mb, nullptr, ttmp, MTOK, DD, 256, 0);
    ln_kernel<2><<<MTOK, 256, 0, stream>>>(ttmp, pe_mg, pe_mbb, tokm, tokmb);

    // ---- attention bias (batched tok_m . tok_m^T) ----
    gemm_bf16<3><<<dim3(2, 2, BB), 256, 0, stream>>>(
        tokmb, tokmb, nullptr, nullptr, biasb, NTOK, NTOK, DD, (long long)NTOK * DD);
    bias_edge_kernel<<<BB, 256, 0, stream>>>(biasb);

    // ---- combine ----
    combine_kernel<<<(MROWS * DD + 255) / 256, 256, 0, stream>>>(toki, tokm, cls, pos, x);

    const int mblk = (MROWS + 127) / 128;   // 50
    const int wqn = 3 * DD * DD, won = DD * DD, w1n = 4 * DD * DD, w2n = 4 * DD * DD;
    const int castTot = (wqn + won + w1n + w2n) / 4;
    for (int l = 0; l < 12; ++l) {
        cast4_kernel<<<(castTot + 255) / 256, 256, 0, stream>>>(
            w_qkv + (size_t)l * wqn, wqn, w_out + (size_t)l * won, won,
            w_fc1 + (size_t)l * w1n, w1n, w_fc2 + (size_t)l * w2n, w2n,
            wqb, wob, w1b, w2b);
        ln_kernel<1><<<MROWS, 256, 0, stream>>>(x, ln1_g + l * DD, ln1_b + l * DD, nullptr, hbuf);
        gemm_bf16<4><<<dim3(3 * DD / 128, mblk), 256, 0, stream>>>(
            hbuf, wqb, b_qkv + l * 3 * DD, nullptr, qkvb, MROWS, 3 * DD, DD, 0);
        attn_kernel<<<dim3(LL, HH, BB), 256, 0, stream>>>(qkvb, biasb, hbuf);
        gemm_bf16<2><<<dim3(DD / 128, mblk), 256, 0, stream>>>(
            hbuf, wob, b_out + l * DD, x, x, MROWS, DD, DD, 0);
        ln_kernel<1><<<MROWS, 256, 0, stream>>>(x, ln2_g + l * DD, ln2_b + l * DD, nullptr, hbuf);
        gemm_bf16<1><<<dim3(4 * DD / 128, mblk), 256, 0, stream>>>(
            hbuf, w1b, b_fc1 + l * 4 * DD, nullptr, fc1b, MROWS, 4 * DD, DD, 0);
        gemm_bf16<2><<<dim3(DD / 128, mblk), 256, 0, stream>>>(
            fc1b, w2b, b_fc2 + l * DD, x, x, MROWS, DD, 4 * DD, 0);
    }
    final_kernel<<<BB, 256, 0, stream>>>(x, enc_g, enc_b, fin_g, fin_b, head_w, head_b, (float*)d_out);
}

// Round 3
// 3900.132 us; speedup vs baseline: 8.7634x; 2.7711x over previous
//
#include <hip/hip_runtime.h>
#include <hip/hip_bf16.h>
#include <math.h>

typedef unsigned int   u32;
typedef unsigned short u16;
typedef __bf16 bf16x8 __attribute__((ext_vector_type(8)));
typedef float  f32x4  __attribute__((ext_vector_type(4)));
typedef u16    u16x8  __attribute__((ext_vector_type(8)));

constexpr int BB = 32, DD = 768, LL = 197, HH = 12, NTOK = 196;
constexpr int MROWS = BB * LL;        // 6304
constexpr int MTOK  = BB * NTOK;      // 6272

__device__ __forceinline__ u16 f2bf(float f) {
    union { float f; u32 u; } v; v.f = f;
    u32 r = v.u + 0x7fff + ((v.u >> 16) & 1);
    return (u16)(r >> 16);
}
__device__ __forceinline__ float bf2f(u16 u) {
    union { u32 u; float f; } v; v.u = ((u32)u) << 16;
    return v.f;
}

#define AS1 __attribute__((address_space(1)))
#define AS3 __attribute__((address_space(3)))
__device__ __forceinline__ void gload_lds16(const void* g, void* l) {
    __builtin_amdgcn_global_load_lds((const AS1 u32*)g, (AS3 u32*)l, 16, 0, 0);
}

// ---------------------------------------------------------------------------
__global__ void cast_kernel(const float* __restrict__ in, u16* __restrict__ out, int n)
{
    int i4 = (blockIdx.x * 256 + threadIdx.x) * 4;
    if (i4 >= n) return;
    float4 v = *reinterpret_cast<const float4*>(in + i4);
    out[i4]   = f2bf(v.x); out[i4+1] = f2bf(v.y);
    out[i4+2] = f2bf(v.z); out[i4+3] = f2bf(v.w);
}

__global__ void cast4_kernel(const float* s0, int n0, const float* s1, int n1,
                             const float* s2, int n2, const float* s3, int n3,
                             u16* d0, u16* d1, u16* d2, u16* d3)
{
    int i4 = (blockIdx.x * 256 + threadIdx.x) * 4;
    const float* s; u16* d; int off;
    if      (i4 < n0)            { s = s0; d = d0; off = i4; }
    else if (i4 < n0+n1)         { s = s1; d = d1; off = i4 - n0; }
    else if (i4 < n0+n1+n2)      { s = s2; d = d2; off = i4 - n0 - n1; }
    else if (i4 < n0+n1+n2+n3)   { s = s3; d = d3; off = i4 - n0 - n1 - n2; }
    else return;
    float4 v = *reinterpret_cast<const float4*>(s + off);
    d[off]   = f2bf(v.x); d[off+1] = f2bf(v.y);
    d[off+2] = f2bf(v.z); d[off+3] = f2bf(v.w);
}

// ---------------------------------------------------------------------------
__global__ void patchify_kernel(const float* __restrict__ src, int C,
                                u16* __restrict__ out, int total)
{
    int idx = blockIdx.x * 256 + threadIdx.x;
    if (idx >= total) return;
    int K = C * 256;
    int row = idx / K, k = idx % K;
    int b = row / NTOK, n = row % NTOK;
    int c = k >> 8, rem = k & 255, pi = rem >> 4, pj = rem & 15;
    int i14 = n / 14, j14 = n % 14;
    float v = src[(((size_t)b * C + c) * 224 + i14 * 16 + pi) * 224 + j14 * 16 + pj];
    out[idx] = f2bf(v);
}

// ---------------------------------------------------------------------------
// bf16 MFMA GEMM (m97 structure), MODEs as before
// ---------------------------------------------------------------------------
template<int MODE>
__global__ __launch_bounds__(256) void gemm_bf16(
    const u16* __restrict__ A, const u16* __restrict__ W,
    const float* __restrict__ bias, const float* __restrict__ res,
    void* __restrict__ Cout, int M, int N, int K, long long strideA)
{
    __shared__ u16 As[128 * 32];
    __shared__ u16 Bs[128 * 32];
    const int tid  = threadIdx.x;
    const int wave = tid >> 6, lane = tid & 63;
    const int wr = wave >> 1, wc = wave & 1;
    const int m0 = blockIdx.y * 128, n0 = blockIdx.x * 128;
    if (MODE == 3) { A += blockIdx.z * strideA; W += blockIdx.z * strideA; }

    const int srow = (wave << 4) + (lane >> 2);
    const int scol = (lane & 3) << 3;
    const int limA = M - 1;
    const int limB = (MODE == 3 ? M : N) - 1;
    int ra0 = m0 + srow;      if (ra0 > limA) ra0 = limA;
    int ra1 = m0 + srow + 64; if (ra1 > limA) ra1 = limA;
    int rb0 = n0 + srow;      if (rb0 > limB) rb0 = limB;
    int rb1 = n0 + srow + 64; if (rb1 > limB) rb1 = limB;

    u16* ldsA0 = &As[wave * 512];
    u16* ldsA1 = &As[2048 + wave * 512];
    u16* ldsB0 = &Bs[wave * 512];
    u16* ldsB1 = &Bs[2048 + wave * 512];

    f32x4 acc[4][4] = {};
    const int rfA = wr * 64 + (lane & 15);
    const int rfB = wc * 64 + (lane & 15);
    const int kc  = (lane >> 4) * 8;

    for (int k0 = 0; k0 < K; k0 += 32) {
        gload_lds16(A + (size_t)ra0 * K + k0 + scol, ldsA0);
        gload_lds16(A + (size_t)ra1 * K + k0 + scol, ldsA1);
        gload_lds16(W + (size_t)rb0 * K + k0 + scol, ldsB0);
        gload_lds16(W + (size_t)rb1 * K + k0 + scol, ldsB1);
        __syncthreads();
        bf16x8 af[4], bf[4];
        #pragma unroll
        for (int i = 0; i < 4; ++i)
            af[i] = *reinterpret_cast<const bf16x8*>(&As[(rfA + i * 16) * 32 + kc]);
        #pragma unroll
        for (int j = 0; j < 4; ++j)
            bf[j] = *reinterpret_cast<const bf16x8*>(&Bs[(rfB + j * 16) * 32 + kc]);
        #pragma unroll
        for (int i = 0; i < 4; ++i)
            #pragma unroll
            for (int j = 0; j < 4; ++j)
                acc[i][j] = __builtin_amdgcn_mfma_f32_16x16x32_bf16(af[i], bf[j], acc[i][j], 0, 0, 0);
        __syncthreads();
    }

    const int cr = (lane >> 4) * 4;
    const int cc = lane & 15;
    #pragma unroll
    for (int i = 0; i < 4; ++i) {
        #pragma unroll
        for (int r = 0; r < 4; ++r) {
            int m = m0 + wr * 64 + i * 16 + cr + r;
            if (MODE != 3 && m >= M) continue;
            #pragma unroll
            for (int j = 0; j < 4; ++j) {
                int n = n0 + wc * 64 + j * 16 + cc;
                float v = acc[i][j][r];
                if (MODE == 0) {
                    ((float*)Cout)[(size_t)m * N + n] = v + bias[n];
                } else if (MODE == 1) {
                    float t = v + bias[n];
                    t = 0.5f * t * (1.f + erff(t * 0.70710678118654752f));
                    ((u16*)Cout)[(size_t)m * N + n] = f2bf(t);
                } else if (MODE == 2) {
                    ((float*)Cout)[(size_t)m * N + n] = v + bias[n] + res[(size_t)m * N + n];
                } else if (MODE == 4) {
                    ((u16*)Cout)[(size_t)m * N + n] = f2bf(v + bias[n]);
                } else { // MODE 3
                    if (m < M && n < M) {
                        float* C3 = (float*)Cout + (size_t)blockIdx.z * LL * LL;
                        C3[(size_t)(m + 1) * LL + (n + 1)] = v * 0.03608439182435161f;
                    }
                }
            }
        }
    }
}

__global__ void bias_edge_kernel(float* __restrict__ bias)
{
    int b = blockIdx.x, t = threadIdx.x;
    if (t < LL) {
        bias[((size_t)b * LL + 0) * LL + t] = 0.f;
        bias[((size_t)b * LL + t) * LL + 0] = 0.f;
    }
}

// ---------------------------------------------------------------------------
__global__ void combine_kernel(
    const float* __restrict__ toki, const float* __restrict__ tokm,
    const float* __restrict__ cls, const float* __restrict__ pos,
    float* __restrict__ x)
{
    size_t idx = (size_t)blockIdx.x * 256 + threadIdx.x;
    if (idx >= (size_t)MROWS * DD) return;
    int d = (int)(idx % DD);
    size_t bl = idx / DD;
    int l = (int)(bl % LL);
    int b = (int)(bl / LL);
    float v;
    if (l == 0) v = cls[d];
    else {
        size_t tix = ((size_t)b * NTOK + (l - 1)) * DD + d;
        v = toki[tix] + 0.5f * tokm[tix];
    }
    x[idx] = v + pos[(size_t)l * DD + d];
}

// ---------------------------------------------------------------------------
template<int OUT>
__global__ __launch_bounds__(256) void ln_kernel(
    const float* __restrict__ in, const float* __restrict__ g,
    const float* __restrict__ beta, float* __restrict__ outf,
    u16* __restrict__ outb)
{
    int row = blockIdx.x;
    int tid = threadIdx.x;
    const float* xr = in + (size_t)row * DD;
    float v[3];
    #pragma unroll
    for (int r = 0; r < 3; ++r) v[r] = xr[tid + r * 256];
    __shared__ float red[256];
    red[tid] = v[0] + v[1] + v[2];
    __syncthreads();
    for (int off = 128; off; off >>= 1) {
        if (tid < off) red[tid] += red[tid + off];
        __syncthreads();
    }
    float mean = red[0] * (1.f / 768.f);
    __syncthreads();
    float q = 0.f;
    #pragma unroll
    for (int r = 0; r < 3; ++r) { float dv = v[r] - mean; q += dv * dv; }
    red[tid] = q;
    __syncthreads();
    for (int off = 128; off; off >>= 1) {
        if (tid < off) red[tid] += red[tid + off];
        __syncthreads();
    }
    float rstd = rsqrtf(red[0] * (1.f / 768.f) + 1e-5f);
    #pragma unroll
    for (int r = 0; r < 3; ++r) {
        int d = tid + r * 256;
        float o = g[d] * (v[r] - mean) * rstd + beta[d];
        if (OUT == 0 || OUT == 2) outf[(size_t)row * DD + d] = o;
        if (OUT == 1 || OUT == 2) outb[(size_t)row * DD + d] = f2bf(o);
    }
}

// ---------------------------------------------------------------------------
// MFMA attention: one block per (h, b). 4 waves; K and V^T staged in LDS;
// each wave owns row-tiles rt = wave, wave+4, ... (16 query rows each).
// S C-layout: row=(lane>>4)*4+reg, col=lane&15. Softmax reduce over the
// 16-lane col group; P -> per-wave LDS strip -> A-frags for PV.
// ---------------------------------------------------------------------------
constexpr int KSTRE = 72;    // K row stride (elems): 144B -> uniform b128 quads
constexpr int VSTRE = 232;   // Vt/P row stride (elems): 464B = 29*16B
constexpr int PSTRE = 232;

__global__ __launch_bounds__(256) void attn_mfma_kernel(
    const u16* __restrict__ qkv, const float* __restrict__ bias,
    u16* __restrict__ o)
{
    const int h = blockIdx.x, b = blockIdx.y;
    const int tid = threadIdx.x, wave = tid >> 6, lane = tid & 63;
    const int lo = lane & 15, hi = lane >> 4;

    __shared__ u16 Ks[208 * KSTRE];       // 29952 B
    __shared__ u16 Vt[64 * VSTRE];        // 29696 B
    __shared__ u16 Ps[4][16 * PSTRE];     // 29696 B

    const u16* qb = qkv + (size_t)b * LL * 2304;

    // stage K rows [208][64], zero past 196
    for (int idx = tid; idx < 208 * 8; idx += 256) {
        int key = idx >> 3, c8 = idx & 7;
        u16x8 v = {};
        if (key < LL) v = *reinterpret_cast<const u16x8*>(qb + (size_t)key * 2304 + 768 + h * 64 + c8 * 8);
        *reinterpret_cast<u16x8*>(&Ks[key * KSTRE + c8 * 8]) = v;
    }
    // stage V transposed [64 d][224 key], zero past 196
    for (int idx = tid; idx < 224 * 8; idx += 256) {
        int key = idx >> 3, c8 = idx & 7;
        u16x8 v = {};
        if (key < LL) v = *reinterpret_cast<const u16x8*>(qb + (size_t)key * 2304 + 1536 + h * 64 + c8 * 8);
        #pragma unroll
        for (int e = 0; e < 8; ++e) Vt[(c8 * 8 + e) * VSTRE + key] = v[e];
    }
    __syncthreads();

    u16* P = Ps[wave];
    const float* biasbb = bias + (size_t)b * LL * LL;

    for (int rt = wave; rt < 13; rt += 4) {
        // Q A-fragments (regs)
        int q = rt * 16 + lo; if (q > LL - 1) q = LL - 1;
        const u16* qrow = qb + (size_t)q * 2304 + h * 64;
        bf16x8 qa0 = *reinterpret_cast<const bf16x8*>(qrow + hi * 8);
        bf16x8 qa1 = *reinterpret_cast<const bf16x8*>(qrow + 32 + hi * 8);

        // QK^T: 13 col tiles
        f32x4 st[13];
        #pragma unroll
        for (int t = 0; t < 13; ++t) {
            int keyc = t * 16 + lo;
            bf16x8 kb0 = *reinterpret_cast<const bf16x8*>(&Ks[keyc * KSTRE + hi * 8]);
            bf16x8 kb1 = *reinterpret_cast<const bf16x8*>(&Ks[keyc * KSTRE + 32 + hi * 8]);
            f32x4 a = {};
            a = __builtin_amdgcn_mfma_f32_16x16x32_bf16(qa0, kb0, a, 0, 0, 0);
            a = __builtin_amdgcn_mfma_f32_16x16x32_bf16(qa1, kb1, a, 0, 0, 0);
            st[t] = a;
        }

        // softmax per output row (reg index r)
        #pragma unroll
        for (int r = 0; r < 4; ++r) {
            int qq = rt * 16 + hi * 4 + r;
            int qc = qq > LL - 1 ? LL - 1 : qq;
            const float* brow = biasbb + (size_t)qc * LL;
            float s[13];
            float m = -1e30f;
            #pragma unroll
            for (int t = 0; t < 13; ++t) {
                int col = t * 16 + lo;
                float v;
                if (col < LL) v = st[t][r] * 0.125f + brow[col];
                else          v = -1e30f;
                s[t] = v;
                m = fmaxf(m, v);
            }
            m = fmaxf(m, __shfl_xor(m, 1));
            m = fmaxf(m, __shfl_xor(m, 2));
            m = fmaxf(m, __shfl_xor(m, 4));
            m = fmaxf(m, __shfl_xor(m, 8));
            float sum = 0.f;
            #pragma unroll
            for (int t = 0; t < 13; ++t) { float e = __expf(s[t] - m); s[t] = e; sum += e; }
            sum += __shfl_xor(sum, 1);
            sum += __shfl_xor(sum, 2);
            sum += __shfl_xor(sum, 4);
            sum += __shfl_xor(sum, 8);
            float inv = 1.f / sum;
            int prow = (hi * 4 + r) * PSTRE;
            #pragma unroll
            for (int t = 0; t < 13; ++t) P[prow + t * 16 + lo] = f2bf(s[t] * inv);
            P[prow + 208 + lo] = 0;   // zero pad cols 208..223
        }

        // PV: O[16 q][64 d] = P[16][224] * V[224][64]
        f32x4 oacc[4] = {};
        #pragma unroll
        for (int kt = 0; kt < 7; ++kt) {
            bf16x8 pa = *reinterpret_cast<const bf16x8*>(&P[lo * PSTRE + kt * 32 + hi * 8]);
            #pragma unroll
            for (int dt = 0; dt < 4; ++dt) {
                bf16x8 vb = *reinterpret_cast<const bf16x8*>(&Vt[(dt * 16 + lo) * VSTRE + kt * 32 + hi * 8]);
                oacc[dt] = __builtin_amdgcn_mfma_f32_16x16x32_bf16(pa, vb, oacc[dt], 0, 0, 0);
            }
        }

        // store O
        #pragma unroll
        for (int dt = 0; dt < 4; ++dt) {
            #pragma unroll
            for (int r = 0; r < 4; ++r) {
                int qq = rt * 16 + hi * 4 + r;
                if (qq < LL)
                    o[((size_t)(b * LL + qq)) * DD + h * 64 + dt * 16 + lo] = f2bf(oacc[dt][r]);
            }
        }
    }
}

// ---------------------------------------------------------------------------
__global__ __launch_bounds__(256) void final_kernel(
    const float* __restrict__ x,
    const float* __restrict__ eg, const float* __restrict__ eb,
    const float* __restrict__ fg, const float* __restrict__ fb,
    const float* __restrict__ hw, const float* __restrict__ hb,
    float* __restrict__ out)
{
    int b = blockIdx.x;
    int tid = threadIdx.x;
    __shared__ float xs[768];
    __shared__ float red[256];
    const float* xr = x + (size_t)b * LL * DD;
    #pragma unroll
    for (int r = 0; r < 3; ++r) xs[tid + r * 256] = xr[tid + r * 256];
    __syncthreads();
    for (int pass = 0; pass < 2; ++pass) {
        const float* g  = pass ? fg : eg;
        const float* bb = pass ? fb : eb;
        red[tid] = xs[tid] + xs[tid + 256] + xs[tid + 512];
        __syncthreads();
        for (int off = 128; off; off >>= 1) {
            if (tid < off) red[tid] += red[tid + off];
            __syncthreads();
        }
        float mean = red[0] * (1.f / 768.f);
        __syncthreads();
        float q = 0.f;
        #pragma unroll
        for (int r = 0; r < 3; ++r) { float dv = xs[tid + r * 256] - mean; q += dv * dv; }
        red[tid] = q;
        __syncthreads();
        for (int off = 128; off; off >>= 1) {
            if (tid < off) red[tid] += red[tid + off];
            __syncthreads();
        }
        float rstd = rsqrtf(red[0] * (1.f / 768.f) + 1e-5f);
        __syncthreads();
        #pragma unroll
        for (int r = 0; r < 3; ++r) {
            int d = tid + r * 256;
            xs[d] = g[d] * (xs[d] - mean) * rstd + bb[d];
        }
        __syncthreads();
    }
    int c = tid >> 6, lane = tid & 63;
    float part = 0.f;
    for (int d = lane; d < 768; d += 64) part += xs[d] * hw[c * 768 + d];
    #pragma unroll
    for (int off = 32; off; off >>= 1) part += __shfl_down(part, off);
    if (lane == 0) out[b * 4 + c] = part + hb[c];
}

// ---------------------------------------------------------------------------
extern "C" void kernel_launch(void* const* d_in, const int* in_sizes, int n_in,
                              void* d_out, int out_size, void* d_ws, size_t ws_size,
                              hipStream_t stream)
{
    const float* img    = (const float*)d_in[0];
    const float* mask   = (const float*)d_in[1];
    const float* pe_iw  = (const float*)d_in[2];
    const float* pe_ib  = (const float*)d_in[3];
    const float* pe_ig  = (const float*)d_in[4];
    const float* pe_ibb = (const float*)d_in[5];
    const float* pe_mw  = (const float*)d_in[6];
    const float* pe_mb  = (const float*)d_in[7];
    const float* pe_mg  = (const float*)d_in[8];
    const float* pe_mbb = (const float*)d_in[9];
    const float* cls    = (const float*)d_in[10];
    const float* pos    = (const float*)d_in[11];
    const float* ln1_g  = (const float*)d_in[12];
    const float* ln1_b  = (const float*)d_in[13];
    const float* w_qkv  = (const float*)d_in[14];
    const float* b_qkv  = (const float*)d_in[15];
    const float* w_out  = (const float*)d_in[16];
    const float* b_out  = (const float*)d_in[17];
    const float* ln2_g  = (const float*)d_in[18];
    const float* ln2_b  = (const float*)d_in[19];
    const float* w_fc1  = (const float*)d_in[20];
    const float* b_fc1  = (const float*)d_in[21];
    const float* w_fc2  = (const float*)d_in[22];
    const float* b_fc2  = (const float*)d_in[23];
    const float* enc_g  = (const float*)d_in[24];
    const float* enc_b  = (const float*)d_in[25];
    const float* fin_g  = (const float*)d_in[26];
    const float* fin_b  = (const float*)d_in[27];
    const float* head_w = (const float*)d_in[28];
    const float* head_b = (const float*)d_in[29];

    char* wsb = (char*)d_ws;
    size_t off = 0;
    auto alloc = [&](size_t bytes) { void* p = wsb + off; off += (bytes + 255) & ~(size_t)255; return p; };

    float* x     = (float*)alloc((size_t)MROWS * DD * 4);
    u16*   qkvb  = (u16*)  alloc((size_t)MROWS * 3 * DD * 2);
    u16*   hbuf  = (u16*)  alloc((size_t)MROWS * DD * 2);
    u16*   fc1b  = (u16*)  alloc((size_t)MROWS * 4 * DD * 2);
    float* biasb = (float*)alloc((size_t)BB * LL * LL * 4);
    u16*   wqb   = (u16*)  alloc((size_t)3 * DD * DD * 2);
    u16*   wob   = (u16*)  alloc((size_t)DD * DD * 2);
    u16*   w1b   = (u16*)  alloc((size_t)4 * DD * DD * 2);
    u16*   w2b   = (u16*)  alloc((size_t)4 * DD * DD * 2);
    float* toki  = (float*)alloc((size_t)MTOK * DD * 4);
    float* tokm  = (float*)alloc((size_t)MTOK * DD * 4);
    u16*   pa    = fc1b;           // patches alias
    float* ttmp  = (float*)qkvb;   // pe-GEMM f32 out alias
    u16*   tokmb = hbuf;           // bf16 tok_m alias

    // ---- patch embed (img) ----
    cast_kernel<<<(DD * DD / 4 + 255) / 256, 256, 0, stream>>>(pe_iw, wob, DD * DD);
    patchify_kernel<<<(MTOK * DD + 255) / 256, 256, 0, stream>>>(img, 3, pa, MTOK * DD);
    gemm_bf16<0><<<dim3(DD / 128, MTOK / 128), 256, 0, stream>>>(
        pa, wob, pe_ib, nullptr, ttmp, MTOK, DD, DD, 0);
    ln_kernel<0><<<MTOK, 256, 0, stream>>>(ttmp, pe_ig, pe_ibb, toki, nullptr);

    // ---- patch embed (mask) ----
    cast_kernel<<<(DD * 256 / 4 + 255) / 256, 256, 0, stream>>>(pe_mw, wob, DD * 256);
    patchify_kernel<<<(MTOK * 256 + 255) / 256, 256, 0, stream>>>(mask, 1, pa, MTOK * 256);
    gemm_bf16<0><<<dim3(DD / 128, MTOK / 128), 256, 0, stream>>>(
        pa, wob, pe_mb, nullptr, ttmp, MTOK, DD, 256, 0);
    ln_kernel<2><<<MTOK, 256, 0, stream>>>(ttmp, pe_mg, pe_mbb, tokm, tokmb);

    // ---- attention bias ----
    gemm_bf16<3><<<dim3(2, 2, BB), 256, 0, stream>>>(
        tokmb, tokmb, nullptr, nullptr, biasb, NTOK, NTOK, DD, (long long)NTOK * DD);
    bias_edge_kernel<<<BB, 256, 0, stream>>>(biasb);

    // ---- combine ----
    combine_kernel<<<(MROWS * DD + 255) / 256, 256, 0, stream>>>(toki, tokm, cls, pos, x);

    const int mblk = (MROWS + 127) / 128;   // 50
    const int wqn = 3 * DD * DD, won = DD * DD, w1n = 4 * DD * DD, w2n = 4 * DD * DD;
    const int castTot = (wqn + won + w1n + w2n) / 4;
    for (int l = 0; l < 12; ++l) {
        cast4_kernel<<<(castTot + 255) / 256, 256, 0, stream>>>(
            w_qkv + (size_t)l * wqn, wqn, w_out + (size_t)l * won, won,
            w_fc1 + (size_t)l * w1n, w1n, w_fc2 + (size_t)l * w2n, w2n,
            wqb, wob, w1b, w2b);
        ln_kernel<1><<<MROWS, 256, 0, stream>>>(x, ln1_g + l * DD, ln1_b + l * DD, nullptr, hbuf);
        gemm_bf16<4><<<dim3(3 * DD / 128, mblk), 256, 0, stream>>>(
            hbuf, wqb, b_qkv + l * 3 * DD, nullptr, qkvb, MROWS, 3 * DD, DD, 0);
        attn_mfma_kernel<<<dim3(HH, BB), 256, 0, stream>>>(qkvb, biasb, hbuf);
        gemm_bf16<2><<<dim3(DD / 128, mblk), 256, 0, stream>>>(
            hbuf, wob, b_out + l * DD, x, x, MROWS, DD, DD, 0);
        ln_kernel<1><<<MROWS, 256, 0, stream>>>(x, ln2_g + l * DD, ln2_b + l * DD, nullptr, hbuf);
        gemm_bf16<1><<<dim3(4 * DD / 128, mblk), 256, 0, stream>>>(
            hbuf, w1b, b_fc1 + l * 4 * DD, nullptr, fc1b, MROWS, 4 * DD, DD, 0);
        gemm_bf16<2><<<dim3(DD / 128, mblk), 256, 0, stream>>>(
            fc1b, w2b, b_fc2 + l * DD, x, x, MROWS, DD, 4 * DD, 0);
    }
    final_kernel<<<BB, 256, 0, stream>>>(x, enc_g, enc_b, fin_g, fin_b, head_w, head_b, (float*)d_out);
}